// Round 2
// baseline (140.857 us; speedup 1.0000x reference)
//
#include <hip/hip_runtime.h>

// Grouped masked GEMM (DeepSeekMOE up/gate + down), fp32 in/out, bf16 MFMA compute.
// G=8, M=32. up/gate: K=4096,N=2816. down: K=1408,N=4096. out: [G,32,5632] f32.
//
// R1: + LDS granule XOR-swizzle (pre-swizzled global source, rule #21 pattern),
//     + v_cvt_pk_bf16_f32 for f32->bf16 (T12 recipe),
//     + 11:16 up/down block interleave for CU load balance.

#define G_    8
#define M_    32
#define KUG   4096
#define NUG   2816
#define KDN   1408
#define NDN   4096
#define NOUT  (NUG + NDN)          // 5632
#define BN    64
#define BK    64
#define NBUP  (G_ * (NUG / BN))    // 8*44 = 352
#define NBDN  (G_ * (NDN / BN))    // 8*64 = 512

typedef __attribute__((ext_vector_type(8))) short    bf16x8;
typedef __attribute__((ext_vector_type(4))) float    f32x4;
typedef __attribute__((ext_vector_type(4))) unsigned u32x4;

typedef __attribute__((address_space(3))) float        lds_f32;
typedef const __attribute__((address_space(1))) float  gbl_f32;

union Frag { u32x4 u; bf16x8 s; };

// one v_cvt_pk_bf16_f32: lo -> bits[15:0], hi -> bits[31:16], RNE
__device__ __forceinline__ unsigned cvtpk(float lo, float hi) {
  unsigned r;
  asm("v_cvt_pk_bf16_f32 %0, %1, %2" : "=v"(r) : "v"(lo), "v"(hi));
  return r;
}

// Read logical granules G and G+1 (16B each) of one LDS row with XOR-swizzle s,
// convert 8 f32 -> bf16x8 fragment. (Granule g of row lives at LDS col (g^s)*4.)
__device__ __forceinline__ bf16x8 cvt_frag(const float* row, int G, int s) {
  f32x4 lo = *(const f32x4*)(row + (((G)     ^ s) << 2));
  f32x4 hi = *(const f32x4*)(row + (((G + 1) ^ s) << 2));
  Frag f;
  f.u[0] = cvtpk(lo[0], lo[1]);
  f.u[1] = cvtpk(lo[2], lo[3]);
  f.u[2] = cvtpk(hi[0], hi[1]);
  f.u[3] = cvtpk(hi[2], hi[3]);
  return f.s;
}

// Stage one BK-tile: W[64][64] + X[32][64] f32. LDS dest is LINEAR (gload_lds
// requirement); the bank-swizzle is applied by permuting the GLOBAL source
// granule within each 256B row: src col-granule = (dest col-granule) ^ (row&7).
// Same involution is applied on the read side -> logical layout unchanged.
__device__ __forceinline__ void stage(float* dst, const float* wg, const float* xg,
                                      int K, int k0, int t) {
#pragma unroll
  for (int rr = 0; rr < 4; ++rr) {            // W tile: 1024 granules of 16B
    int gr  = rr * 256 + t;
    int row = gr >> 4;
    int col = ((gr & 15) ^ (row & 7)) << 2;
    __builtin_amdgcn_global_load_lds((gbl_f32*)(wg + (size_t)row * K + k0 + col),
                                     (lds_f32*)(dst + gr * 4), 16, 0, 0);
  }
#pragma unroll
  for (int rr = 0; rr < 2; ++rr) {            // X tile: 512 granules
    int gr  = rr * 256 + t;
    int row = gr >> 4;
    int col = ((gr & 15) ^ (row & 7)) << 2;
    __builtin_amdgcn_global_load_lds((gbl_f32*)(xg + (size_t)row * K + k0 + col),
                                     (lds_f32*)(dst + 4096 + gr * 4), 16, 0, 0);
  }
}

__global__ __launch_bounds__(256, 3) void moe_masked_gemm(
    const float* __restrict__ x_ug, const float* __restrict__ w_ug,
    const float* __restrict__ x_dn, const float* __restrict__ w_dn,
    const int* __restrict__ masked_m, float* __restrict__ out) {
  __shared__ float lds[2][64 * 64 + 32 * 64];  // W tile + X tile, double buffered (48 KB)

  // 11:16 interleave: every 27 consecutive blocks = 11 up + 16 down, so each
  // CU's resident set mixes long (64-iter) and short (22-iter) blocks.
  int p = blockIdx.x;
  int period = p / 27, slot = p - period * 27;
  int b = (slot < 11) ? (period * 11 + slot) : (NBUP + period * 16 + (slot - 11));

  const float* xg;
  const float* wg;
  int K, NIT, g, nb, colOff;
  if (b < NBUP) {
    g = b / 44; nb = b - g * 44;
    K = KUG; NIT = KUG / BK; colOff = 0;
    wg = w_ug + ((size_t)g * NUG + (size_t)nb * BN) * KUG;
    xg = x_ug + (size_t)g * M_ * KUG;
  } else {
    int b2 = b - NBUP;
    g = b2 >> 6; nb = b2 & 63;
    K = KDN; NIT = KDN / BK; colOff = NUG;
    wg = w_dn + ((size_t)g * NDN + (size_t)nb * BN) * KDN;
    xg = x_dn + (size_t)g * M_ * KDN;
  }

  int t  = threadIdx.x;
  int mm = masked_m[g];
  float* outg = out + (size_t)g * M_ * NOUT + colOff + (size_t)nb * BN;

  if (mm == 0) {                    // whole group's rows masked: zeros, skip all reads
#pragma unroll
    for (int i = 0; i < 8; ++i) {
      int e = i * 256 + t;
      outg[(size_t)(e >> 6) * NOUT + (e & 63)] = 0.f;
    }
    return;
  }

  int lane = t & 63, wv = t >> 6;   // wave 0..3 owns n-cols [wv*16, wv*16+16)
  int r = lane & 15, kb = lane >> 4;
  int s = r & 7;                    // read-side swizzle (row&7 for all rows this lane reads)

  f32x4 acc0 = {0.f, 0.f, 0.f, 0.f};
  f32x4 acc1 = {0.f, 0.f, 0.f, 0.f};

  stage(&lds[0][0], wg, xg, K, 0, t);
  __syncthreads();

  int cur = 0;
  for (int it = 0; it < NIT; ++it) {
    if (it + 1 < NIT) stage(&lds[cur ^ 1][0], wg, xg, K, (it + 1) * BK, t);

    const float* Ws = &lds[cur][0];       // [64][64] f32 (granule-swizzled rows)
    const float* Xs = Ws + 64 * 64;       // [32][64] f32
#pragma unroll
    for (int kc = 0; kc < 2; ++kc) {
      int G = kc * 8 + kb * 2;            // lane's logical granule within the row
      bf16x8 a0 = cvt_frag(Xs + r * 64,              G, s);
      bf16x8 a1 = cvt_frag(Xs + (r + 16) * 64,       G, s);
      bf16x8 bb = cvt_frag(Ws + (wv * 16 + r) * 64,  G, s);
      acc0 = __builtin_amdgcn_mfma_f32_16x16x32_bf16(a0, bb, acc0, 0, 0, 0);
      acc1 = __builtin_amdgcn_mfma_f32_16x16x32_bf16(a1, bb, acc1, 0, 0, 0);
    }
    __syncthreads();                      // drains our gload_lds (vmcnt) + ds_reads (lgkm)
    cur ^= 1;
  }

  // Epilogue: C/D layout col=lane&15, row=(lane>>4)*4+i (m89-verified). Mask rows >= mm.
  float* op = outg + wv * 16 + r;
  int m0 = kb * 4;
#pragma unroll
  for (int i = 0; i < 4; ++i) {
    op[(size_t)(m0 + i) * NOUT]      = (m0 + i      < mm) ? acc0[i] : 0.f;
    op[(size_t)(m0 + i + 16) * NOUT] = (m0 + i + 16 < mm) ? acc1[i] : 0.f;
  }
}

extern "C" void kernel_launch(void* const* d_in, const int* in_sizes, int n_in,
                              void* d_out, int out_size, void* d_ws, size_t ws_size,
                              hipStream_t stream) {
  const float* x_ug     = (const float*)d_in[0];
  const float* w_ug     = (const float*)d_in[1];
  const float* x_dn     = (const float*)d_in[2];
  const float* w_dn     = (const float*)d_in[3];
  const int*   masked_m = (const int*)d_in[4];
  float*       out      = (float*)d_out;

  moe_masked_gemm<<<dim3(NBUP + NBDN), dim3(256), 0, stream>>>(
      x_ug, w_ug, x_dn, w_dn, masked_m, out);
}

// Round 3
// 136.655 us; speedup vs baseline: 1.0308x; 1.0308x over previous
//
#include <hip/hip_runtime.h>
#include <hip/hip_bf16.h>

// Grouped masked GEMM (DeepSeekMOE up/gate + down), fp32 in/out, bf16 MFMA compute.
// G=8, M=32. up/gate: K=4096,N=2816. down: K=1408,N=4096. out: [G,32,5632] f32.
//
// R2: T4 counted-vmcnt 3-buffer pipeline (never drain vmcnt mid-loop),
//     raw s_barrier (1 per iter), compiler-generated bf16 cvt (m240),
//     keep R1's source-side LDS granule swizzle + 11:16 block interleave.

#define G_    8
#define M_    32
#define KUG   4096
#define NUG   2816
#define KDN   1408
#define NDN   4096
#define NOUT  (NUG + NDN)          // 5632
#define BN    64
#define BK    64
#define NBUP  (G_ * (NUG / BN))    // 8*44 = 352
#define NBDN  (G_ * (NDN / BN))    // 8*64 = 512
#define TILEF (64 * 64 + 32 * 64)  // floats per buffer (W + X) = 6144 (24 KB)

typedef __attribute__((ext_vector_type(8))) short    bf16x8;
typedef __attribute__((ext_vector_type(4))) float    f32x4;

typedef __attribute__((address_space(3))) float        lds_f32;
typedef const __attribute__((address_space(1))) float  gbl_f32;

// barrier + counted waitcnt as inline asm with "memory" clobber: keeps the
// compiler from hoisting LDS reads above them (rule #18 analog for vmcnt).
#define ASM_BARRIER()   asm volatile("s_barrier" ::: "memory")
#define VMCNT(n)        asm volatile("s_waitcnt vmcnt(" #n ")" ::: "memory")

// fp32 -> bf16 RNE via compiler (emits v_cvt_pk_bf16_f32 pairs; m240: do NOT
// hand-write the asm).
__device__ __forceinline__ short f2bf(float x) {
  union { __hip_bfloat16 h; short s; } u;
  u.h = __hip_bfloat16(x);
  return u.s;
}

// Read logical granules G,G+1 (16B each) of one LDS row with XOR-swizzle s,
// convert 8 f32 -> bf16x8 fragment. (Granule g of a row lives at col (g^s)*4.)
__device__ __forceinline__ bf16x8 cvt_frag(const float* row, int Gr, int s) {
  f32x4 lo = *(const f32x4*)(row + (((Gr)     ^ s) << 2));
  f32x4 hi = *(const f32x4*)(row + (((Gr + 1) ^ s) << 2));
  bf16x8 o;
#pragma unroll
  for (int j = 0; j < 4; ++j) { o[j] = f2bf(lo[j]); o[4 + j] = f2bf(hi[j]); }
  return o;
}

// Stage one BK-tile: W[64][64] + X[32][64] f32, 6 global_load_lds (16B) per
// thread. LDS dest LINEAR (gload_lds requirement); bank-swizzle achieved by
// permuting the GLOBAL source granule within each 256B row (rule #21 pattern):
// src granule = dest granule ^ (row&7). Same XOR applied on the read side.
__device__ __forceinline__ void stage(float* dst, const float* wg, const float* xg,
                                      int K, int k0, int t) {
#pragma unroll
  for (int rr = 0; rr < 4; ++rr) {            // W tile: 1024 granules of 16B
    int gr  = rr * 256 + t;
    int row = gr >> 4;
    int col = ((gr & 15) ^ (row & 7)) << 2;
    __builtin_amdgcn_global_load_lds((gbl_f32*)(wg + (size_t)row * K + k0 + col),
                                     (lds_f32*)(dst + gr * 4), 16, 0, 0);
  }
#pragma unroll
  for (int rr = 0; rr < 2; ++rr) {            // X tile: 512 granules
    int gr  = rr * 256 + t;
    int row = gr >> 4;
    int col = ((gr & 15) ^ (row & 7)) << 2;
    __builtin_amdgcn_global_load_lds((gbl_f32*)(xg + (size_t)row * K + k0 + col),
                                     (lds_f32*)(dst + 4096 + gr * 4), 16, 0, 0);
  }
}

__global__ __launch_bounds__(256, 2) void moe_masked_gemm(
    const float* __restrict__ x_ug, const float* __restrict__ w_ug,
    const float* __restrict__ x_dn, const float* __restrict__ w_dn,
    const int* __restrict__ masked_m, float* __restrict__ out) {
  __shared__ float lds[3][TILEF];   // 3-deep pipeline, 72 KB -> 2 blocks/CU

  // 11:16 interleave: every 27 consecutive blocks = 11 up + 16 down, so each
  // CU's resident set mixes long (64-iter) and short (22-iter) blocks.
  int p = blockIdx.x;
  int period = p / 27, slot = p - period * 27;
  int b = (slot < 11) ? (period * 11 + slot) : (NBUP + period * 16 + (slot - 11));

  const float* xg;
  const float* wg;
  int K, NIT, g, nb, colOff;
  if (b < NBUP) {
    g = b / 44; nb = b - g * 44;
    K = KUG; NIT = KUG / BK; colOff = 0;
    wg = w_ug + ((size_t)g * NUG + (size_t)nb * BN) * KUG;
    xg = x_ug + (size_t)g * M_ * KUG;
  } else {
    int b2 = b - NBUP;
    g = b2 >> 6; nb = b2 & 63;
    K = KDN; NIT = KDN / BK; colOff = NUG;
    wg = w_dn + ((size_t)g * NDN + (size_t)nb * BN) * KDN;
    xg = x_dn + (size_t)g * M_ * KDN;
  }

  int t  = threadIdx.x;
  int mm = masked_m[g];
  float* outg = out + (size_t)g * M_ * NOUT + colOff + (size_t)nb * BN;

  if (mm == 0) {                    // whole group's rows masked: zeros, skip all reads
#pragma unroll
    for (int i = 0; i < 8; ++i) {
      int e = i * 256 + t;
      outg[(size_t)(e >> 6) * NOUT + (e & 63)] = 0.f;
    }
    return;
  }

  int lane = t & 63, wv = t >> 6;   // wave 0..3 owns n-cols [wv*16, wv*16+16)
  int r = lane & 15, kb = lane >> 4;
  int s = r & 7;                    // read-side swizzle key (row&7 for this lane's rows)

  f32x4 acc0 = {0.f, 0.f, 0.f, 0.f};
  f32x4 acc1 = {0.f, 0.f, 0.f, 0.f};

  // Prologue: tiles 0 and 1 in flight (12 outstanding gload_lds per thread).
  stage(&lds[0][0], wg, xg, K, 0, t);
  if (NIT > 1) stage(&lds[1][0], wg, xg, K, BK, t);

  int cur = 0;                      // = it % 3
  for (int it = 0; it < NIT; ++it) {
    // Oldest 6 loads (tile it) done; tile it+1's 6 stay in flight across the
    // barrier (T4: never drain to 0 mid-loop). Last iter: full drain.
    if (it + 1 < NIT) { VMCNT(6); } else { VMCNT(0); }
    ASM_BARRIER();                  // all waves' tile-it DMA now visible

    // Safe to overwrite buf[(it+2)%3] == buf[(it-1)%3]: every wave finished
    // compute(it-1) before this barrier (program order).
    if (it + 2 < NIT) {
      int nx = cur + 2; if (nx >= 3) nx -= 3;
      stage(&lds[nx][0], wg, xg, K, (it + 2) * BK, t);
    }

    const float* Ws = &lds[cur][0];       // [64][64] f32 (granule-swizzled rows)
    const float* Xs = Ws + 64 * 64;       // [32][64] f32
#pragma unroll
    for (int kc = 0; kc < 2; ++kc) {
      int Gr = kc * 8 + kb * 2;           // lane's logical granule within its row
      bf16x8 a0 = cvt_frag(Xs + r * 64,             Gr, s);
      bf16x8 a1 = cvt_frag(Xs + (r + 16) * 64,      Gr, s);
      bf16x8 bb = cvt_frag(Ws + (wv * 16 + r) * 64, Gr, s);
      acc0 = __builtin_amdgcn_mfma_f32_16x16x32_bf16(a0, bb, acc0, 0, 0, 0);
      acc1 = __builtin_amdgcn_mfma_f32_16x16x32_bf16(a1, bb, acc1, 0, 0, 0);
    }

    cur += 1; if (cur >= 3) cur -= 3;
  }

  // Epilogue: C/D layout col=lane&15, row=(lane>>4)*4+i (m89-verified). Mask rows >= mm.
  float* op = outg + wv * 16 + r;
  int m0 = kb * 4;
#pragma unroll
  for (int i = 0; i < 4; ++i) {
    op[(size_t)(m0 + i) * NOUT]      = (m0 + i      < mm) ? acc0[i] : 0.f;
    op[(size_t)(m0 + i + 16) * NOUT] = (m0 + i + 16 < mm) ? acc1[i] : 0.f;
  }
}

extern "C" void kernel_launch(void* const* d_in, const int* in_sizes, int n_in,
                              void* d_out, int out_size, void* d_ws, size_t ws_size,
                              hipStream_t stream) {
  const float* x_ug     = (const float*)d_in[0];
  const float* w_ug     = (const float*)d_in[1];
  const float* x_dn     = (const float*)d_in[2];
  const float* w_dn     = (const float*)d_in[3];
  const int*   masked_m = (const int*)d_in[4];
  float*       out      = (float*)d_out;

  moe_masked_gemm<<<dim3(NBUP + NBDN), dim3(256), 0, stream>>>(
      x_ug, w_ug, x_dn, w_dn, masked_m, out);
}